// Round 1
// baseline (4621.873 us; speedup 1.0000x reference)
//
#include <hip/hip_runtime.h>

// GNN: 3x (GCNConv -> BN -> ReLU) -> mean/max pool per graph -> 3-layer MLP.
// N=50000 nodes, E=800000 edges, F=H=128, G=1024 graphs.
// conv bias cancels inside BatchNorm (mean-subtraction) -> skipped entirely.

constexpr int FH = 128;     // feature dim
constexpr int GG = 1024;    // graphs
constexpr float EPSV = 1e-5f;

// ---------------- degree / norm ----------------
__global__ void k_deg(const int* __restrict__ dst, unsigned* __restrict__ deg, int E) {
    int e = blockIdx.x * 256 + threadIdx.x;
    if (e < E) atomicAdd(&deg[dst[e]], 1u);
}

__global__ void k_dinv(const unsigned* __restrict__ deg, float* __restrict__ dinv, int n) {
    int i = blockIdx.x * 256 + threadIdx.x;
    if (i < n) dinv[i] = rsqrtf((float)deg[i] + 1.0f);  // +1 = self loop
}

// ---------------- GEMM: H = X @ W, (n x 128) @ (128 x 128) ----------------
#define TM 64
__global__ __launch_bounds__(256) void k_gemm(const float* __restrict__ X,
                                              const float* __restrict__ W,
                                              float* __restrict__ H, int n) {
    __shared__ float xs[TM][128];          // 32 KB
    int row0 = blockIdx.x * TM;
    int tid = threadIdx.x;
    const float4* Xv = (const float4*)X;   // row stride = 32 float4
    float4* xsv = (float4*)xs;
    #pragma unroll
    for (int i = 0; i < TM * 32 / 256; ++i) {
        int idx = tid + i * 256;
        int r = idx >> 5, c = idx & 31;
        float4 v = make_float4(0.f, 0.f, 0.f, 0.f);
        if (row0 + r < n) v = Xv[(size_t)(row0 + r) * 32 + c];
        xsv[idx] = v;
    }
    __syncthreads();
    int tn = tid & 15, tm = tid >> 4;
    int c0 = tn * 8, r0 = tm * 4;
    float acc[4][8];
    #pragma unroll
    for (int r = 0; r < 4; ++r)
        #pragma unroll
        for (int c = 0; c < 8; ++c) acc[r][c] = 0.f;
    const float4* Wv = (const float4*)W;   // W cached in L1/L2 (64 KB, reused by all blocks)
    #pragma unroll 4
    for (int kb = 0; kb < 32; ++kb) {
        int k4 = kb * 4;
        float4 xv[4];
        #pragma unroll
        for (int r = 0; r < 4; ++r) xv[r] = *(const float4*)&xs[r0 + r][k4];
        #pragma unroll
        for (int kk = 0; kk < 4; ++kk) {
            float4 w0 = Wv[(k4 + kk) * 32 + tn * 2];
            float4 w1 = Wv[(k4 + kk) * 32 + tn * 2 + 1];
            #pragma unroll
            for (int r = 0; r < 4; ++r) {
                float x = ((const float*)&xv[r])[kk];
                acc[r][0] = fmaf(x, w0.x, acc[r][0]);
                acc[r][1] = fmaf(x, w0.y, acc[r][1]);
                acc[r][2] = fmaf(x, w0.z, acc[r][2]);
                acc[r][3] = fmaf(x, w0.w, acc[r][3]);
                acc[r][4] = fmaf(x, w1.x, acc[r][4]);
                acc[r][5] = fmaf(x, w1.y, acc[r][5]);
                acc[r][6] = fmaf(x, w1.z, acc[r][6]);
                acc[r][7] = fmaf(x, w1.w, acc[r][7]);
            }
        }
    }
    #pragma unroll
    for (int r = 0; r < 4; ++r) {
        int row = row0 + r0 + r;
        if (row < n) {
            float4 o0 = make_float4(acc[r][0], acc[r][1], acc[r][2], acc[r][3]);
            float4 o1 = make_float4(acc[r][4], acc[r][5], acc[r][6], acc[r][7]);
            *(float4*)&H[(size_t)row * 128 + c0] = o0;
            *(float4*)&H[(size_t)row * 128 + c0 + 4] = o1;
        }
    }
}

// ---------------- self-loop init: A[n][f] = H[n][f] * dinv[n]^2 ----------------
__global__ void k_selfloop(const float* __restrict__ H, const float* __restrict__ dinv,
                           float* __restrict__ A, int n) {
    int idx = blockIdx.x * 256 + threadIdx.x;   // float4 index
    if (idx >= n * 32) return;
    int node = idx >> 5;
    float dv = dinv[node];
    float nrm = dv * dv;
    float4 h = ((const float4*)H)[idx];
    ((float4*)A)[idx] = make_float4(h.x * nrm, h.y * nrm, h.z * nrm, h.w * nrm);
}

// ---------------- edge scatter: A[dst] += H[src] * dinv[src]*dinv[dst] ----------------
__global__ __launch_bounds__(256) void k_scatter(const int* __restrict__ src, const int* __restrict__ dst,
                                                 const float* __restrict__ dinv, const float* __restrict__ H,
                                                 float* __restrict__ A, int E) {
    int t = blockIdx.x * 256 + threadIdx.x;
    int e = t >> 5;                  // 32 threads per edge, float4 each
    if (e >= E) return;
    int lane = t & 31;
    int s = src[e], d = dst[e];
    float nrm = dinv[s] * dinv[d];
    float4 h = *(const float4*)&H[(size_t)s * 128 + lane * 4];
    float* out = &A[(size_t)d * 128 + lane * 4];
    unsafeAtomicAdd(out + 0, h.x * nrm);
    unsafeAtomicAdd(out + 1, h.y * nrm);
    unsafeAtomicAdd(out + 2, h.z * nrm);
    unsafeAtomicAdd(out + 3, h.w * nrm);
}

// ---------------- BN stats: per-feature sum & sumsq ----------------
__global__ __launch_bounds__(256) void k_stats(const float* __restrict__ X, float* __restrict__ stats, int n) {
    __shared__ float s0[256], s1[256];
    int tid = threadIdx.x;
    int f = tid & 127, sub = tid >> 7;
    float s = 0.f, ss = 0.f;
    for (int r = blockIdx.x * 2 + sub; r < n; r += gridDim.x * 2) {
        float v = X[(size_t)r * 128 + f];
        s += v;
        ss = fmaf(v, v, ss);
    }
    s0[tid] = s; s1[tid] = ss;
    __syncthreads();
    if (tid < 128) {
        unsafeAtomicAdd(&stats[f], s0[tid] + s0[tid + 128]);
        unsafeAtomicAdd(&stats[128 + f], s1[tid] + s1[tid + 128]);
    }
}

// ---------------- BN apply + ReLU ----------------
__global__ void k_apply(const float* __restrict__ Ain, const float* __restrict__ stats,
                        const float* __restrict__ gamma, const float* __restrict__ beta,
                        float* __restrict__ Xout, int n) {
    int idx = blockIdx.x * 256 + threadIdx.x;   // float4 index
    if (idx >= n * 32) return;
    int f4 = idx & 31;
    float invN = 1.0f / (float)n;
    float4 a  = ((const float4*)Ain)[idx];
    float4 s  = ((const float4*)stats)[f4];
    float4 q  = ((const float4*)stats)[32 + f4];
    float4 gm = ((const float4*)gamma)[f4];
    float4 bt = ((const float4*)beta)[f4];
    float4 o;
    {
        float mu = s.x * invN; float var = fmaf(-mu, mu, q.x * invN);
        o.x = fmaxf(fmaf(gm.x * rsqrtf(var + EPSV), a.x - mu, bt.x), 0.f);
    }
    {
        float mu = s.y * invN; float var = fmaf(-mu, mu, q.y * invN);
        o.y = fmaxf(fmaf(gm.y * rsqrtf(var + EPSV), a.y - mu, bt.y), 0.f);
    }
    {
        float mu = s.z * invN; float var = fmaf(-mu, mu, q.z * invN);
        o.z = fmaxf(fmaf(gm.z * rsqrtf(var + EPSV), a.z - mu, bt.z), 0.f);
    }
    {
        float mu = s.w * invN; float var = fmaf(-mu, mu, q.w * invN);
        o.w = fmaxf(fmaf(gm.w * rsqrtf(var + EPSV), a.w - mu, bt.w), 0.f);
    }
    ((float4*)Xout)[idx] = o;
}

// ---------------- pooling: counts, sum, max (values >= 0 after ReLU) ----------------
__global__ void k_pool(const float* __restrict__ X, const int* __restrict__ batch,
                       unsigned* __restrict__ cnt, float* __restrict__ psum,
                       unsigned* __restrict__ pmax, int n) {
    int idx = blockIdx.x * 256 + threadIdx.x;   // float4 index
    if (idx >= n * 32) return;
    int node = idx >> 5, f4 = idx & 31;
    int g = batch[node];
    if (f4 == 0) atomicAdd(&cnt[g], 1u);
    float4 v = ((const float4*)X)[idx];
    float* ps = &psum[(size_t)g * 128 + f4 * 4];
    unsafeAtomicAdd(ps + 0, v.x);
    unsafeAtomicAdd(ps + 1, v.y);
    unsafeAtomicAdd(ps + 2, v.z);
    unsafeAtomicAdd(ps + 3, v.w);
    unsigned* pm = &pmax[(size_t)g * 128 + f4 * 4];
    atomicMax(pm + 0, __float_as_uint(v.x));   // valid: all values >= +0
    atomicMax(pm + 1, __float_as_uint(v.y));
    atomicMax(pm + 2, __float_as_uint(v.z));
    atomicMax(pm + 3, __float_as_uint(v.w));
}

// ---------------- MLP ----------------
__global__ __launch_bounds__(256) void k_mlp1(const unsigned* __restrict__ cnt, const float* __restrict__ psum,
                                              const unsigned* __restrict__ pmax, const float* __restrict__ W1,
                                              const float* __restrict__ b1, float* __restrict__ H1) {
    __shared__ float grow[256];
    int gi = blockIdx.x, t = threadIdx.x;
    if (t < 128) {
        float c = fmaxf((float)cnt[gi], 1.0f);
        grow[t] = psum[gi * 128 + t] / c;
    } else {
        grow[t] = __uint_as_float(pmax[gi * 128 + (t - 128)]);
    }
    __syncthreads();
    float acc = b1[t];
    #pragma unroll 8
    for (int k = 0; k < 256; ++k) acc = fmaf(grow[k], W1[k * 256 + t], acc);
    H1[gi * 256 + t] = fmaxf(acc, 0.f);
}

__global__ __launch_bounds__(128) void k_mlp2(const float* __restrict__ H1, const float* __restrict__ W2,
                                              const float* __restrict__ b2, float* __restrict__ H2) {
    __shared__ float row[256];
    int gi = blockIdx.x, t = threadIdx.x;
    row[t] = H1[gi * 256 + t];
    row[t + 128] = H1[gi * 256 + t + 128];
    __syncthreads();
    float acc = b2[t];
    #pragma unroll 8
    for (int k = 0; k < 256; ++k) acc = fmaf(row[k], W2[k * 128 + t], acc);
    H2[gi * 128 + t] = fmaxf(acc, 0.f);
}

__global__ __launch_bounds__(256) void k_mlp3(const float* __restrict__ H2, const float* __restrict__ W3,
                                              const float* __restrict__ b3, float* __restrict__ out) {
    int gi = blockIdx.x * 4 + (threadIdx.x >> 6);
    int lane = threadIdx.x & 63;
    float v = H2[gi * 128 + lane] * W3[lane] + H2[gi * 128 + 64 + lane] * W3[64 + lane];
    #pragma unroll
    for (int off = 32; off; off >>= 1) v += __shfl_down(v, off);
    if (lane == 0) out[gi] = v + b3[0];
}

extern "C" void kernel_launch(void* const* d_in, const int* in_sizes, int n_in,
                              void* d_out, int out_size, void* d_ws, size_t ws_size,
                              hipStream_t stream) {
    const float* x      = (const float*)d_in[0];
    const int*   ei     = (const int*)d_in[1];
    const int*   batch  = (const int*)d_in[2];
    const float* convW0 = (const float*)d_in[3];
    const float* convW  = (const float*)d_in[4];
    // d_in[5] convb: cancels inside BatchNorm, unused
    const float* gamma  = (const float*)d_in[6];
    const float* beta   = (const float*)d_in[7];
    const float* mW1    = (const float*)d_in[8];
    const float* mb1    = (const float*)d_in[9];
    const float* mW2    = (const float*)d_in[10];
    const float* mb2    = (const float*)d_in[11];
    const float* mW3    = (const float*)d_in[12];
    const float* mb3    = (const float*)d_in[13];
    float* out = (float*)d_out;

    const int E = in_sizes[1] / 2;
    const int n = in_sizes[0] / FH;

    // workspace layout (all counts multiples of 4 -> float4-aligned)
    float*    A     = (float*)d_ws;                       // n*128
    float*    B     = A + (size_t)n * FH;                 // n*128
    float*    dinv  = B + (size_t)n * FH;                 // n
    unsigned* deg   = (unsigned*)(dinv + n);              // n
    float*    stats = (float*)(deg + n);                  // 256
    unsigned* cnt   = (unsigned*)(stats + 256);           // G
    float*    psum  = (float*)(cnt + GG);                 // G*128
    unsigned* pmax  = (unsigned*)(psum + (size_t)GG * FH);// G*128
    float*    h1    = (float*)(pmax + (size_t)GG * FH);   // G*256
    float*    h2    = h1 + (size_t)GG * 256;              // G*128

    const int* srcI = ei;
    const int* dstI = ei + E;

    hipMemsetAsync(deg, 0, (size_t)n * sizeof(unsigned), stream);
    k_deg<<<(E + 255) / 256, 256, 0, stream>>>(dstI, deg, E);
    k_dinv<<<(n + 255) / 256, 256, 0, stream>>>(deg, dinv, n);

    const float* Ws[3] = {convW0, convW, convW + FH * FH};
    float* bufs[2] = {A, B};
    const float* xin = x;
    const int elem4 = n * 32;

    for (int l = 0; l < 3; ++l) {
        float* hbuf = bufs[l & 1];
        float* abuf = bufs[(l & 1) ^ 1];
        float* xout = hbuf;   // h dead after scatter; reuse as layer output
        k_gemm<<<(n + TM - 1) / TM, 256, 0, stream>>>(xin, Ws[l], hbuf, n);
        k_selfloop<<<(elem4 + 255) / 256, 256, 0, stream>>>(hbuf, dinv, abuf, n);
        k_scatter<<<(E * 32 + 255) / 256, 256, 0, stream>>>(srcI, dstI, dinv, hbuf, abuf, E);
        hipMemsetAsync(stats, 0, 256 * sizeof(float), stream);
        k_stats<<<512, 256, 0, stream>>>(abuf, stats, n);
        k_apply<<<(elem4 + 255) / 256, 256, 0, stream>>>(abuf, stats, gamma + l * FH, beta + l * FH, xout, n);
        xin = xout;
    }

    // pooling accumulators: cnt | psum | pmax contiguous -> one memset (0 bits = +0.0, valid max-identity)
    hipMemsetAsync(cnt, 0, (size_t)(GG + 2 * GG * FH) * sizeof(unsigned), stream);
    k_pool<<<(elem4 + 255) / 256, 256, 0, stream>>>(xin, batch, cnt, psum, pmax, n);

    k_mlp1<<<GG, 256, 0, stream>>>(cnt, psum, pmax, mW1, mb1, h1);
    k_mlp2<<<GG, 128, 0, stream>>>(h1, mW2, mb2, h2);
    k_mlp3<<<GG / 4, 256, 0, stream>>>(h2, mW3, mb3, out);
}

// Round 2
// 858.689 us; speedup vs baseline: 5.3825x; 5.3825x over previous
//
#include <hip/hip_runtime.h>

// GNN: 3x (GCNConv -> BN -> ReLU) -> mean/max pool per graph -> 3-layer MLP.
// N=50000 nodes, E=800000 edges, F=H=128, G=1024 graphs.
// conv bias cancels inside BatchNorm (mean-subtraction) -> skipped entirely.
// Aggregation is pull-style over a CSR built per launch (no f32 atomics):
//   H2 = (X@W) * dinv[row]  (GEMM epilogue)
//   A[d] = dinv[d] * (H2[d] + sum_{s in N(d)} H2[s])

constexpr int FH = 128;     // feature dim
constexpr int GG = 1024;    // graphs
constexpr float EPSV = 1e-5f;

// ---------------- degree ----------------
__global__ void k_deg(const int* __restrict__ dst, unsigned* __restrict__ deg, int E) {
    int e = blockIdx.x * 256 + threadIdx.x;
    if (e < E) atomicAdd(&deg[dst[e]], 1u);
}

__global__ void k_dinv(const unsigned* __restrict__ deg, float* __restrict__ dinv, int n) {
    int i = blockIdx.x * 256 + threadIdx.x;
    if (i < n) dinv[i] = rsqrtf((float)deg[i] + 1.0f);  // +1 = self loop
}

// ---------------- exclusive prefix scan of deg -> rowptr & cursor (single block) ----------------
__global__ __launch_bounds__(1024) void k_scan(const unsigned* __restrict__ deg, int* __restrict__ rowptr,
                                               int* __restrict__ cursor, int n) {
    __shared__ int wsum[16];
    __shared__ int s_carry;
    int lane = threadIdx.x & 63, wid = threadIdx.x >> 6;
    if (threadIdx.x == 0) s_carry = 0;
    __syncthreads();
    int nchunks = (n + 1023) / 1024;
    for (int c = 0; c < nchunks; ++c) {
        int i = c * 1024 + threadIdx.x;
        int v = (i < n) ? (int)deg[i] : 0;
        int incl = v;
        #pragma unroll
        for (int off = 1; off < 64; off <<= 1) {
            int t = __shfl_up(incl, off, 64);
            if (lane >= off) incl += t;
        }
        if (lane == 63) wsum[wid] = incl;
        __syncthreads();
        int woff = 0;
        #pragma unroll
        for (int w = 0; w < 16; ++w) woff += (w < wid) ? wsum[w] : 0;
        int carry = s_carry;
        int excl = carry + woff + incl - v;
        if (i < n) { rowptr[i] = excl; cursor[i] = excl; }
        __syncthreads();
        if (threadIdx.x == 1023) s_carry = excl + v;   // carry + chunk total
        __syncthreads();
    }
    if (threadIdx.x == 0) rowptr[n] = s_carry;
}

// ---------------- CSR fill: group edge sources by dst ----------------
__global__ void k_fill(const int* __restrict__ src, const int* __restrict__ dst,
                       int* __restrict__ cursor, int* __restrict__ csr_src, int E) {
    int e = blockIdx.x * 256 + threadIdx.x;
    if (e < E) {
        int p = atomicAdd(&cursor[dst[e]], 1);
        csr_src[p] = src[e];
    }
}

// ---------------- GEMM: H2 = (X @ W) * dinv[row], (n x 128) @ (128 x 128) ----------------
#define TM 64
__global__ __launch_bounds__(256) void k_gemm(const float* __restrict__ X,
                                              const float* __restrict__ W,
                                              const float* __restrict__ dinv,
                                              float* __restrict__ H, int n) {
    __shared__ float xs[TM][128];          // 32 KB
    int row0 = blockIdx.x * TM;
    int tid = threadIdx.x;
    const float4* Xv = (const float4*)X;   // row stride = 32 float4
    float4* xsv = (float4*)xs;
    #pragma unroll
    for (int i = 0; i < TM * 32 / 256; ++i) {
        int idx = tid + i * 256;
        int r = idx >> 5, c = idx & 31;
        float4 v = make_float4(0.f, 0.f, 0.f, 0.f);
        if (row0 + r < n) v = Xv[(size_t)(row0 + r) * 32 + c];
        xsv[idx] = v;
    }
    __syncthreads();
    int tn = tid & 15, tm = tid >> 4;
    int c0 = tn * 8, r0 = tm * 4;
    float acc[4][8];
    #pragma unroll
    for (int r = 0; r < 4; ++r)
        #pragma unroll
        for (int c = 0; c < 8; ++c) acc[r][c] = 0.f;
    const float4* Wv = (const float4*)W;   // W cached in L1/L2 (64 KB, reused by all blocks)
    #pragma unroll 4
    for (int kb = 0; kb < 32; ++kb) {
        int k4 = kb * 4;
        float4 xv[4];
        #pragma unroll
        for (int r = 0; r < 4; ++r) xv[r] = *(const float4*)&xs[r0 + r][k4];
        #pragma unroll
        for (int kk = 0; kk < 4; ++kk) {
            float4 w0 = Wv[(k4 + kk) * 32 + tn * 2];
            float4 w1 = Wv[(k4 + kk) * 32 + tn * 2 + 1];
            #pragma unroll
            for (int r = 0; r < 4; ++r) {
                float x = ((const float*)&xv[r])[kk];
                acc[r][0] = fmaf(x, w0.x, acc[r][0]);
                acc[r][1] = fmaf(x, w0.y, acc[r][1]);
                acc[r][2] = fmaf(x, w0.z, acc[r][2]);
                acc[r][3] = fmaf(x, w0.w, acc[r][3]);
                acc[r][4] = fmaf(x, w1.x, acc[r][4]);
                acc[r][5] = fmaf(x, w1.y, acc[r][5]);
                acc[r][6] = fmaf(x, w1.z, acc[r][6]);
                acc[r][7] = fmaf(x, w1.w, acc[r][7]);
            }
        }
    }
    #pragma unroll
    for (int r = 0; r < 4; ++r) {
        int row = row0 + r0 + r;
        if (row < n) {
            float dv = dinv[row];
            float4 o0 = make_float4(acc[r][0] * dv, acc[r][1] * dv, acc[r][2] * dv, acc[r][3] * dv);
            float4 o1 = make_float4(acc[r][4] * dv, acc[r][5] * dv, acc[r][6] * dv, acc[r][7] * dv);
            *(float4*)&H[(size_t)row * 128 + c0] = o0;
            *(float4*)&H[(size_t)row * 128 + c0 + 4] = o1;
        }
    }
}

// ---------------- pull aggregation: A[d] = dinv[d] * (H2[d] + sum H2[src]) ----------------
__global__ __launch_bounds__(256) void k_aggregate(const int* __restrict__ rowptr, const int* __restrict__ csr_src,
                                                   const float* __restrict__ dinv, const float* __restrict__ H2,
                                                   float* __restrict__ A, int n) {
    int node = blockIdx.x * 8 + (threadIdx.x >> 5);
    if (node >= n) return;
    int lane = threadIdx.x & 31;
    int beg = rowptr[node], end = rowptr[node + 1];
    float dv = dinv[node];
    float4 acc = *(const float4*)&H2[(size_t)node * 128 + lane * 4];  // self loop
    float4 acc2 = make_float4(0.f, 0.f, 0.f, 0.f);
    int e = beg;
    for (; e + 1 < end; e += 2) {
        int s0 = csr_src[e], s1 = csr_src[e + 1];
        float4 h0 = *(const float4*)&H2[(size_t)s0 * 128 + lane * 4];
        float4 h1 = *(const float4*)&H2[(size_t)s1 * 128 + lane * 4];
        acc.x += h0.x;  acc.y += h0.y;  acc.z += h0.z;  acc.w += h0.w;
        acc2.x += h1.x; acc2.y += h1.y; acc2.z += h1.z; acc2.w += h1.w;
    }
    if (e < end) {
        int s0 = csr_src[e];
        float4 h0 = *(const float4*)&H2[(size_t)s0 * 128 + lane * 4];
        acc.x += h0.x; acc.y += h0.y; acc.z += h0.z; acc.w += h0.w;
    }
    acc.x = (acc.x + acc2.x) * dv;
    acc.y = (acc.y + acc2.y) * dv;
    acc.z = (acc.z + acc2.z) * dv;
    acc.w = (acc.w + acc2.w) * dv;
    *(float4*)&A[(size_t)node * 128 + lane * 4] = acc;
}

// ---------------- BN stats: per-feature sum & sumsq ----------------
__global__ __launch_bounds__(256) void k_stats(const float* __restrict__ X, float* __restrict__ stats, int n) {
    __shared__ float s0[256], s1[256];
    int tid = threadIdx.x;
    int f = tid & 127, sub = tid >> 7;
    float s = 0.f, ss = 0.f;
    for (int r = blockIdx.x * 2 + sub; r < n; r += gridDim.x * 2) {
        float v = X[(size_t)r * 128 + f];
        s += v;
        ss = fmaf(v, v, ss);
    }
    s0[tid] = s; s1[tid] = ss;
    __syncthreads();
    if (tid < 128) {
        unsafeAtomicAdd(&stats[f], s0[tid] + s0[tid + 128]);
        unsafeAtomicAdd(&stats[128 + f], s1[tid] + s1[tid + 128]);
    }
}

// ---------------- BN apply + ReLU ----------------
__global__ void k_apply(const float* __restrict__ Ain, const float* __restrict__ stats,
                        const float* __restrict__ gamma, const float* __restrict__ beta,
                        float* __restrict__ Xout, int n) {
    int idx = blockIdx.x * 256 + threadIdx.x;   // float4 index
    if (idx >= n * 32) return;
    int f4 = idx & 31;
    float invN = 1.0f / (float)n;
    float4 a  = ((const float4*)Ain)[idx];
    float4 s  = ((const float4*)stats)[f4];
    float4 q  = ((const float4*)stats)[32 + f4];
    float4 gm = ((const float4*)gamma)[f4];
    float4 bt = ((const float4*)beta)[f4];
    float4 o;
    {
        float mu = s.x * invN; float var = fmaf(-mu, mu, q.x * invN);
        o.x = fmaxf(fmaf(gm.x * rsqrtf(var + EPSV), a.x - mu, bt.x), 0.f);
    }
    {
        float mu = s.y * invN; float var = fmaf(-mu, mu, q.y * invN);
        o.y = fmaxf(fmaf(gm.y * rsqrtf(var + EPSV), a.y - mu, bt.y), 0.f);
    }
    {
        float mu = s.z * invN; float var = fmaf(-mu, mu, q.z * invN);
        o.z = fmaxf(fmaf(gm.z * rsqrtf(var + EPSV), a.z - mu, bt.z), 0.f);
    }
    {
        float mu = s.w * invN; float var = fmaf(-mu, mu, q.w * invN);
        o.w = fmaxf(fmaf(gm.w * rsqrtf(var + EPSV), a.w - mu, bt.w), 0.f);
    }
    ((float4*)Xout)[idx] = o;
}

// ---------------- pooling: counts, sum, max (values >= 0 after ReLU) ----------------
__global__ void k_pool(const float* __restrict__ X, const int* __restrict__ batch,
                       unsigned* __restrict__ cnt, float* __restrict__ psum,
                       unsigned* __restrict__ pmax, int n) {
    int idx = blockIdx.x * 256 + threadIdx.x;   // float4 index
    if (idx >= n * 32) return;
    int node = idx >> 5, f4 = idx & 31;
    int g = batch[node];
    if (f4 == 0) atomicAdd(&cnt[g], 1u);
    float4 v = ((const float4*)X)[idx];
    float* ps = &psum[(size_t)g * 128 + f4 * 4];
    unsafeAtomicAdd(ps + 0, v.x);
    unsafeAtomicAdd(ps + 1, v.y);
    unsafeAtomicAdd(ps + 2, v.z);
    unsafeAtomicAdd(ps + 3, v.w);
    unsigned* pm = &pmax[(size_t)g * 128 + f4 * 4];
    atomicMax(pm + 0, __float_as_uint(v.x));   // valid: all values >= +0
    atomicMax(pm + 1, __float_as_uint(v.y));
    atomicMax(pm + 2, __float_as_uint(v.z));
    atomicMax(pm + 3, __float_as_uint(v.w));
}

// ---------------- MLP ----------------
__global__ __launch_bounds__(256) void k_mlp1(const unsigned* __restrict__ cnt, const float* __restrict__ psum,
                                              const unsigned* __restrict__ pmax, const float* __restrict__ W1,
                                              const float* __restrict__ b1, float* __restrict__ H1) {
    __shared__ float grow[256];
    int gi = blockIdx.x, t = threadIdx.x;
    if (t < 128) {
        float c = fmaxf((float)cnt[gi], 1.0f);
        grow[t] = psum[gi * 128 + t] / c;
    } else {
        grow[t] = __uint_as_float(pmax[gi * 128 + (t - 128)]);
    }
    __syncthreads();
    float acc = b1[t];
    #pragma unroll 8
    for (int k = 0; k < 256; ++k) acc = fmaf(grow[k], W1[k * 256 + t], acc);
    H1[gi * 256 + t] = fmaxf(acc, 0.f);
}

__global__ __launch_bounds__(128) void k_mlp2(const float* __restrict__ H1, const float* __restrict__ W2,
                                              const float* __restrict__ b2, float* __restrict__ H2) {
    __shared__ float row[256];
    int gi = blockIdx.x, t = threadIdx.x;
    row[t] = H1[gi * 256 + t];
    row[t + 128] = H1[gi * 256 + t + 128];
    __syncthreads();
    float acc = b2[t];
    #pragma unroll 8
    for (int k = 0; k < 256; ++k) acc = fmaf(row[k], W2[k * 128 + t], acc);
    H2[gi * 128 + t] = fmaxf(acc, 0.f);
}

__global__ __launch_bounds__(256) void k_mlp3(const float* __restrict__ H2, const float* __restrict__ W3,
                                              const float* __restrict__ b3, float* __restrict__ out) {
    int gi = blockIdx.x * 4 + (threadIdx.x >> 6);
    int lane = threadIdx.x & 63;
    float v = H2[gi * 128 + lane] * W3[lane] + H2[gi * 128 + 64 + lane] * W3[64 + lane];
    #pragma unroll
    for (int off = 32; off; off >>= 1) v += __shfl_down(v, off);
    if (lane == 0) out[gi] = v + b3[0];
}

extern "C" void kernel_launch(void* const* d_in, const int* in_sizes, int n_in,
                              void* d_out, int out_size, void* d_ws, size_t ws_size,
                              hipStream_t stream) {
    const float* x      = (const float*)d_in[0];
    const int*   ei     = (const int*)d_in[1];
    const int*   batch  = (const int*)d_in[2];
    const float* convW0 = (const float*)d_in[3];
    const float* convW  = (const float*)d_in[4];
    // d_in[5] convb: cancels inside BatchNorm, unused
    const float* gamma  = (const float*)d_in[6];
    const float* beta   = (const float*)d_in[7];
    const float* mW1    = (const float*)d_in[8];
    const float* mb1    = (const float*)d_in[9];
    const float* mW2    = (const float*)d_in[10];
    const float* mb2    = (const float*)d_in[11];
    const float* mW3    = (const float*)d_in[12];
    const float* mb3    = (const float*)d_in[13];
    float* out = (float*)d_out;

    const int E = in_sizes[1] / 2;
    const int n = in_sizes[0] / FH;
    const int npad = (n + 4) & ~3;

    // workspace layout (all counts multiples of 4 -> float4-aligned)
    float*    A      = (float*)d_ws;                        // n*128
    float*    B      = A + (size_t)n * FH;                  // n*128
    float*    dinv   = B + (size_t)n * FH;                  // n
    unsigned* deg    = (unsigned*)(dinv + n);               // n
    float*    stats  = (float*)(deg + n);                   // 256
    unsigned* cnt    = (unsigned*)(stats + 256);            // G
    float*    psum   = (float*)(cnt + GG);                  // G*128
    unsigned* pmax   = (unsigned*)(psum + (size_t)GG * FH); // G*128
    float*    h1     = (float*)(pmax + (size_t)GG * FH);    // G*256
    float*    h2     = h1 + (size_t)GG * 256;               // G*128
    int*      rowptr = (int*)(h2 + (size_t)GG * FH);        // n+1 (padded)
    int*      cursor = rowptr + npad;                       // n
    int*      csrsrc = cursor + npad;                       // E

    const int* srcI = ei;
    const int* dstI = ei + E;

    // ---- CSR build ----
    hipMemsetAsync(deg, 0, (size_t)n * sizeof(unsigned), stream);
    k_deg<<<(E + 255) / 256, 256, 0, stream>>>(dstI, deg, E);
    k_dinv<<<(n + 255) / 256, 256, 0, stream>>>(deg, dinv, n);
    k_scan<<<1, 1024, 0, stream>>>(deg, rowptr, cursor, n);
    k_fill<<<(E + 255) / 256, 256, 0, stream>>>(srcI, dstI, cursor, csrsrc, E);

    const float* Ws[3] = {convW0, convW, convW + FH * FH};
    float* bufs[2] = {A, B};
    const float* xin = x;
    const int elem4 = n * 32;

    for (int l = 0; l < 3; ++l) {
        float* hbuf = bufs[l & 1];
        float* abuf = bufs[(l & 1) ^ 1];
        float* xout = hbuf;   // H2 dead after aggregate; reuse as layer output
        k_gemm<<<(n + TM - 1) / TM, 256, 0, stream>>>(xin, Ws[l], dinv, hbuf, n);
        k_aggregate<<<(n + 7) / 8, 256, 0, stream>>>(rowptr, csrsrc, dinv, hbuf, abuf, n);
        hipMemsetAsync(stats, 0, 256 * sizeof(float), stream);
        k_stats<<<512, 256, 0, stream>>>(abuf, stats, n);
        k_apply<<<(elem4 + 255) / 256, 256, 0, stream>>>(abuf, stats, gamma + l * FH, beta + l * FH, xout, n);
        xin = xout;
    }

    // pooling accumulators: cnt | psum | pmax contiguous -> one memset (0 bits = +0.0, valid max-identity)
    hipMemsetAsync(cnt, 0, (size_t)(GG + 2 * GG * FH) * sizeof(unsigned), stream);
    k_pool<<<(elem4 + 255) / 256, 256, 0, stream>>>(xin, batch, cnt, psum, pmax, n);

    k_mlp1<<<GG, 256, 0, stream>>>(cnt, psum, pmax, mW1, mb1, h1);
    k_mlp2<<<GG, 128, 0, stream>>>(h1, mW2, mb2, h2);
    k_mlp3<<<GG / 4, 256, 0, stream>>>(h2, mW3, mb3, out);
}

// Round 3
// 668.869 us; speedup vs baseline: 6.9100x; 1.2838x over previous
//
#include <hip/hip_runtime.h>

// GNN: 3x (GCNConv -> BN -> ReLU) -> mean/max pool per graph -> 3-layer MLP.
// N=50000 nodes, E=800000 edges, F=H=128, G=1024 graphs.
// conv bias cancels inside BatchNorm (mean-subtraction) -> skipped entirely.
// Aggregation: pull-style over CSR (no f32 atomics).
// BN-apply+ReLU is folded into the NEXT consumer (GEMM staging / pooling) via
// per-feature scale/shift; pooling uses sorted `batch` (binary-searched
// boundaries) -> no pooling atomics either.

constexpr int FH = 128;     // feature dim
constexpr int GG = 1024;    // graphs
constexpr int NSB = 256;    // stats partial blocks
constexpr float EPSV = 1e-5f;

// ---------------- degree ----------------
__global__ void k_deg(const int* __restrict__ dst, unsigned* __restrict__ deg, int E) {
    int e = blockIdx.x * 256 + threadIdx.x;
    if (e < E) atomicAdd(&deg[dst[e]], 1u);
}

__global__ void k_dinv(const unsigned* __restrict__ deg, float* __restrict__ dinv, int n) {
    int i = blockIdx.x * 256 + threadIdx.x;
    if (i < n) dinv[i] = rsqrtf((float)deg[i] + 1.0f);  // +1 = self loop
}

// ---------------- exclusive prefix scan of deg -> rowptr & cursor (single block) ----------------
__global__ __launch_bounds__(1024) void k_scan(const unsigned* __restrict__ deg, int* __restrict__ rowptr,
                                               int* __restrict__ cursor, int n) {
    __shared__ int wsum[16];
    __shared__ int s_carry;
    int lane = threadIdx.x & 63, wid = threadIdx.x >> 6;
    if (threadIdx.x == 0) s_carry = 0;
    __syncthreads();
    int nchunks = (n + 1023) / 1024;
    for (int c = 0; c < nchunks; ++c) {
        int i = c * 1024 + threadIdx.x;
        int v = (i < n) ? (int)deg[i] : 0;
        int incl = v;
        #pragma unroll
        for (int off = 1; off < 64; off <<= 1) {
            int t = __shfl_up(incl, off, 64);
            if (lane >= off) incl += t;
        }
        if (lane == 63) wsum[wid] = incl;
        __syncthreads();
        int woff = 0;
        #pragma unroll
        for (int w = 0; w < 16; ++w) woff += (w < wid) ? wsum[w] : 0;
        int carry = s_carry;
        int excl = carry + woff + incl - v;
        if (i < n) { rowptr[i] = excl; cursor[i] = excl; }
        __syncthreads();
        if (threadIdx.x == 1023) s_carry = excl + v;   // carry + chunk total
        __syncthreads();
    }
    if (threadIdx.x == 0) rowptr[n] = s_carry;
}

// ---------------- CSR fill: group edge sources by dst ----------------
__global__ void k_fill(const int* __restrict__ src, const int* __restrict__ dst,
                       int* __restrict__ cursor, int* __restrict__ csr_src, int E) {
    int e = blockIdx.x * 256 + threadIdx.x;
    if (e < E) {
        int p = atomicAdd(&cursor[dst[e]], 1);
        csr_src[p] = src[e];
    }
}

// ---------------- graph boundaries from sorted batch ----------------
__global__ void k_gptr(const int* __restrict__ batch, int* __restrict__ gptr, int n) {
    int g = blockIdx.x * 256 + threadIdx.x;
    if (g > GG) return;
    int lo = 0, hi = n;                       // first index with batch[i] >= g
    while (lo < hi) { int mid = (lo + hi) >> 1; if (batch[mid] < g) lo = mid + 1; else hi = mid; }
    gptr[g] = lo;
}

// ---------------- GEMM: H2 = (bn(X) @ W) * dinv[row] ----------------
// If sc!=null, staged X gets x*sc[f]+sh[f], relu (fused BN of previous layer).
#define TM 64
__global__ __launch_bounds__(256) void k_gemm(const float* __restrict__ X,
                                              const float* __restrict__ W,
                                              const float* __restrict__ dinv,
                                              const float* __restrict__ sc,
                                              const float* __restrict__ sh,
                                              float* __restrict__ H, int n) {
    __shared__ float xs[TM][128];          // 32 KB
    int row0 = blockIdx.x * TM;
    int tid = threadIdx.x;
    const float4* Xv = (const float4*)X;   // row stride = 32 float4
    float4* xsv = (float4*)xs;
    #pragma unroll
    for (int i = 0; i < TM * 32 / 256; ++i) {
        int idx = tid + i * 256;
        int r = idx >> 5, c = idx & 31;
        float4 v = make_float4(0.f, 0.f, 0.f, 0.f);
        if (row0 + r < n) v = Xv[(size_t)(row0 + r) * 32 + c];
        if (sc) {
            float4 s4 = ((const float4*)sc)[c];
            float4 h4 = ((const float4*)sh)[c];
            v.x = fmaxf(fmaf(v.x, s4.x, h4.x), 0.f);
            v.y = fmaxf(fmaf(v.y, s4.y, h4.y), 0.f);
            v.z = fmaxf(fmaf(v.z, s4.z, h4.z), 0.f);
            v.w = fmaxf(fmaf(v.w, s4.w, h4.w), 0.f);
        }
        xsv[idx] = v;
    }
    __syncthreads();
    int tn = tid & 15, tm = tid >> 4;
    int c0 = tn * 8, r0 = tm * 4;
    float acc[4][8];
    #pragma unroll
    for (int r = 0; r < 4; ++r)
        #pragma unroll
        for (int c = 0; c < 8; ++c) acc[r][c] = 0.f;
    const float4* Wv = (const float4*)W;   // W cached in L1/L2 (64 KB, reused by all blocks)
    #pragma unroll 4
    for (int kb = 0; kb < 32; ++kb) {
        int k4 = kb * 4;
        float4 xv[4];
        #pragma unroll
        for (int r = 0; r < 4; ++r) xv[r] = *(const float4*)&xs[r0 + r][k4];
        #pragma unroll
        for (int kk = 0; kk < 4; ++kk) {
            float4 w0 = Wv[(k4 + kk) * 32 + tn * 2];
            float4 w1 = Wv[(k4 + kk) * 32 + tn * 2 + 1];
            #pragma unroll
            for (int r = 0; r < 4; ++r) {
                float x = ((const float*)&xv[r])[kk];
                acc[r][0] = fmaf(x, w0.x, acc[r][0]);
                acc[r][1] = fmaf(x, w0.y, acc[r][1]);
                acc[r][2] = fmaf(x, w0.z, acc[r][2]);
                acc[r][3] = fmaf(x, w0.w, acc[r][3]);
                acc[r][4] = fmaf(x, w1.x, acc[r][4]);
                acc[r][5] = fmaf(x, w1.y, acc[r][5]);
                acc[r][6] = fmaf(x, w1.z, acc[r][6]);
                acc[r][7] = fmaf(x, w1.w, acc[r][7]);
            }
        }
    }
    #pragma unroll
    for (int r = 0; r < 4; ++r) {
        int row = row0 + r0 + r;
        if (row < n) {
            float dv = dinv[row];
            float4 o0 = make_float4(acc[r][0] * dv, acc[r][1] * dv, acc[r][2] * dv, acc[r][3] * dv);
            float4 o1 = make_float4(acc[r][4] * dv, acc[r][5] * dv, acc[r][6] * dv, acc[r][7] * dv);
            *(float4*)&H[(size_t)row * 128 + c0] = o0;
            *(float4*)&H[(size_t)row * 128 + c0 + 4] = o1;
        }
    }
}

// ---------------- pull aggregation: A[d] = dinv[d] * (H2[d] + sum H2[src]) ----------------
__global__ __launch_bounds__(256) void k_aggregate(const int* __restrict__ rowptr, const int* __restrict__ csr_src,
                                                   const float* __restrict__ dinv, const float* __restrict__ H2,
                                                   float* __restrict__ A, int n) {
    int node = blockIdx.x * 8 + (threadIdx.x >> 5);
    if (node >= n) return;
    int lane = threadIdx.x & 31;
    int beg = rowptr[node], end = rowptr[node + 1];
    float dv = dinv[node];
    float4 acc = *(const float4*)&H2[(size_t)node * 128 + lane * 4];  // self loop
    float4 acc2 = make_float4(0.f, 0.f, 0.f, 0.f);
    int e = beg;
    for (; e + 1 < end; e += 2) {
        int s0 = csr_src[e], s1 = csr_src[e + 1];
        float4 h0 = *(const float4*)&H2[(size_t)s0 * 128 + lane * 4];
        float4 h1 = *(const float4*)&H2[(size_t)s1 * 128 + lane * 4];
        acc.x += h0.x;  acc.y += h0.y;  acc.z += h0.z;  acc.w += h0.w;
        acc2.x += h1.x; acc2.y += h1.y; acc2.z += h1.z; acc2.w += h1.w;
    }
    if (e < end) {
        int s0 = csr_src[e];
        float4 h0 = *(const float4*)&H2[(size_t)s0 * 128 + lane * 4];
        acc.x += h0.x; acc.y += h0.y; acc.z += h0.z; acc.w += h0.w;
    }
    acc.x = (acc.x + acc2.x) * dv;
    acc.y = (acc.y + acc2.y) * dv;
    acc.z = (acc.z + acc2.z) * dv;
    acc.w = (acc.w + acc2.w) * dv;
    *(float4*)&A[(size_t)node * 128 + lane * 4] = acc;
}

// ---------------- BN stats: per-block partial sum & sumsq (no atomics) ----------------
__global__ __launch_bounds__(256) void k_stats(const float* __restrict__ X, float* __restrict__ partials, int n) {
    __shared__ float s0[256], s1[256];
    int tid = threadIdx.x;
    int f = tid & 127, sub = tid >> 7;
    float s = 0.f, ss = 0.f;
    for (int r = blockIdx.x * 2 + sub; r < n; r += NSB * 2) {
        float v = X[(size_t)r * 128 + f];
        s += v;
        ss = fmaf(v, v, ss);
    }
    s0[tid] = s; s1[tid] = ss;
    __syncthreads();
    if (tid < 128) {
        partials[(size_t)blockIdx.x * 256 + f]       = s0[tid] + s0[tid + 128];
        partials[(size_t)blockIdx.x * 256 + 128 + f] = s1[tid] + s1[tid + 128];
    }
}

// ---------------- finalize stats -> scale/shift ----------------
__global__ __launch_bounds__(128) void k_finstats(const float* __restrict__ partials,
                                                  const float* __restrict__ gamma, const float* __restrict__ beta,
                                                  float* __restrict__ sc, float* __restrict__ sh, int n) {
    int f = threadIdx.x;
    float s = 0.f, q = 0.f;
    for (int b = 0; b < NSB; ++b) {
        s += partials[(size_t)b * 256 + f];
        q += partials[(size_t)b * 256 + 128 + f];
    }
    float invN = 1.0f / (float)n;
    float mu = s * invN;
    float var = fmaf(-mu, mu, q * invN);
    float scale = gamma[f] * rsqrtf(var + EPSV);
    sc[f] = scale;
    sh[f] = fmaf(-mu, scale, beta[f]);
}

// ---------------- pooling over sorted batch: mean & max, fused final BN+ReLU ----------------
__global__ __launch_bounds__(256) void k_pool(const float* __restrict__ X, const int* __restrict__ gptr,
                                              const float* __restrict__ sc, const float* __restrict__ sh,
                                              float* __restrict__ pooled) {
    __shared__ float shm[256];
    int g = blockIdx.x;
    int t = threadIdx.x;
    int f = t & 127, sub = t >> 7;
    int beg = gptr[g], end = gptr[g + 1];
    float scf = sc[f], shf = sh[f];
    float s = 0.f, m = 0.f;
    for (int r = beg + sub; r < end; r += 2) {
        float v = fmaxf(fmaf(X[(size_t)r * 128 + f], scf, shf), 0.f);
        s += v; m = fmaxf(m, v);
    }
    shm[t] = s;
    __syncthreads();
    if (sub == 0) {
        int c = end - beg;
        float inv = (c > 0) ? 1.0f / (float)c : 0.f;
        pooled[(size_t)g * 256 + f] = (s + shm[t + 128]) * inv;
    }
    __syncthreads();
    shm[t] = m;
    __syncthreads();
    if (sub == 1) {
        pooled[(size_t)g * 256 + 128 + f] = fmaxf(m, shm[t - 128]);  // 0 for empty graph = reference
    }
}

// ---------------- MLP ----------------
__global__ __launch_bounds__(256) void k_mlp1(const float* __restrict__ pooled, const float* __restrict__ W1,
                                              const float* __restrict__ b1, float* __restrict__ H1) {
    __shared__ float grow[256];
    int gi = blockIdx.x, t = threadIdx.x;
    grow[t] = pooled[(size_t)gi * 256 + t];
    __syncthreads();
    float acc = b1[t];
    #pragma unroll 8
    for (int k = 0; k < 256; ++k) acc = fmaf(grow[k], W1[k * 256 + t], acc);
    H1[gi * 256 + t] = fmaxf(acc, 0.f);
}

__global__ __launch_bounds__(128) void k_mlp2(const float* __restrict__ H1, const float* __restrict__ W2,
                                              const float* __restrict__ b2, float* __restrict__ H2) {
    __shared__ float row[256];
    int gi = blockIdx.x, t = threadIdx.x;
    row[t] = H1[gi * 256 + t];
    row[t + 128] = H1[gi * 256 + t + 128];
    __syncthreads();
    float acc = b2[t];
    #pragma unroll 8
    for (int k = 0; k < 256; ++k) acc = fmaf(row[k], W2[k * 128 + t], acc);
    H2[gi * 128 + t] = fmaxf(acc, 0.f);
}

__global__ __launch_bounds__(256) void k_mlp3(const float* __restrict__ H2, const float* __restrict__ W3,
                                              const float* __restrict__ b3, float* __restrict__ out) {
    int gi = blockIdx.x * 4 + (threadIdx.x >> 6);
    int lane = threadIdx.x & 63;
    float v = H2[gi * 128 + lane] * W3[lane] + H2[gi * 128 + 64 + lane] * W3[64 + lane];
    #pragma unroll
    for (int off = 32; off; off >>= 1) v += __shfl_down(v, off);
    if (lane == 0) out[gi] = v + b3[0];
}

extern "C" void kernel_launch(void* const* d_in, const int* in_sizes, int n_in,
                              void* d_out, int out_size, void* d_ws, size_t ws_size,
                              hipStream_t stream) {
    const float* x      = (const float*)d_in[0];
    const int*   ei     = (const int*)d_in[1];
    const int*   batch  = (const int*)d_in[2];
    const float* convW0 = (const float*)d_in[3];
    const float* convW  = (const float*)d_in[4];
    // d_in[5] convb: cancels inside BatchNorm, unused
    const float* gamma  = (const float*)d_in[6];
    const float* beta   = (const float*)d_in[7];
    const float* mW1    = (const float*)d_in[8];
    const float* mb1    = (const float*)d_in[9];
    const float* mW2    = (const float*)d_in[10];
    const float* mb2    = (const float*)d_in[11];
    const float* mW3    = (const float*)d_in[12];
    const float* mb3    = (const float*)d_in[13];
    float* out = (float*)d_out;

    const int E = in_sizes[1] / 2;
    const int n = in_sizes[0] / FH;
    const int npad = (n + 4) & ~3;

    // workspace layout (float4-aligned chunks)
    float*    A       = (float*)d_ws;                         // n*128  (H2)
    float*    B       = A + (size_t)n * FH;                   // n*128  (aggregate out)
    float*    dinv    = B + (size_t)n * FH;                   // n
    unsigned* deg     = (unsigned*)(dinv + n);                // n
    float*    parts   = (float*)(deg + n);                    // NSB*256
    float*    sc      = parts + (size_t)NSB * 256;            // 128
    float*    sh      = sc + 128;                             // 128
    float*    pooled  = sh + 128;                             // G*256
    float*    h1      = pooled + (size_t)GG * 256;            // G*256
    float*    h2      = h1 + (size_t)GG * 256;                // G*128
    int*      gptr    = (int*)(h2 + (size_t)GG * FH);         // G+1 (pad 4)
    int*      rowptr  = gptr + ((GG + 4) & ~3);               // n+1 (padded)
    int*      cursor  = rowptr + npad;                        // n
    int*      csrsrc  = cursor + npad;                        // E

    const int* srcI = ei;
    const int* dstI = ei + E;

    // ---- CSR build + graph boundaries ----
    hipMemsetAsync(deg, 0, (size_t)n * sizeof(unsigned), stream);
    k_deg<<<(E + 255) / 256, 256, 0, stream>>>(dstI, deg, E);
    k_dinv<<<(n + 255) / 256, 256, 0, stream>>>(deg, dinv, n);
    k_scan<<<1, 1024, 0, stream>>>(deg, rowptr, cursor, n);
    k_fill<<<(E + 255) / 256, 256, 0, stream>>>(srcI, dstI, cursor, csrsrc, E);
    k_gptr<<<(GG + 1 + 255) / 256, 256, 0, stream>>>(batch, gptr, n);

    const float* Ws[3] = {convW0, convW, convW + FH * FH};
    const float* xin = x;

    for (int l = 0; l < 3; ++l) {
        const float* scl = (l == 0) ? nullptr : sc;
        const float* shl = (l == 0) ? nullptr : sh;
        k_gemm<<<(n + TM - 1) / TM, 256, 0, stream>>>(xin, Ws[l], dinv, scl, shl, A, n);
        k_aggregate<<<(n + 7) / 8, 256, 0, stream>>>(rowptr, csrsrc, dinv, A, B, n);
        k_stats<<<NSB, 256, 0, stream>>>(B, parts, n);
        k_finstats<<<1, 128, 0, stream>>>(parts, gamma + l * FH, beta + l * FH, sc, sh, n);
        xin = B;   // next GEMM applies sc/sh on the fly
    }

    // pooling (applies layer-3 BN+ReLU on the fly), then MLP
    k_pool<<<GG, 256, 0, stream>>>(B, gptr, sc, sh, pooled);
    k_mlp1<<<GG, 256, 0, stream>>>(pooled, mW1, mb1, h1);
    k_mlp2<<<GG, 128, 0, stream>>>(h1, mW2, mb2, h2);
    k_mlp3<<<GG / 4, 256, 0, stream>>>(h2, mW3, mb3, out);
}

// Round 4
// 559.324 us; speedup vs baseline: 8.2633x; 1.1959x over previous
//
#include <hip/hip_runtime.h>

// GNN: 3x (GCNConv -> BN -> ReLU) -> mean/max pool per graph -> 3-layer MLP.
// N=50000 nodes, E=800000 edges, F=H=128, G=1024 graphs.
// conv bias cancels inside BatchNorm (mean-subtraction) -> skipped entirely.
// Aggregation: pull-style over CSR (no f32 atomics); H2 stored bf16 to halve
// the random-gather fetch (one RNE quantization/layer, BN renormalizes).
// BN-apply+ReLU folded into the NEXT consumer (GEMM staging / pooling).
// Pooling uses sorted `batch` (binary-searched boundaries) -> no atomics.

constexpr int FH = 128;     // feature dim
constexpr int GG = 1024;    // graphs
constexpr int NSB = 256;    // stats partial blocks
constexpr float EPSV = 1e-5f;

__device__ inline unsigned short bf16_rn(float x) {
    unsigned u = __float_as_uint(x);
    unsigned r = (u + 0x7FFFu + ((u >> 16) & 1u)) >> 16;
    return (unsigned short)r;
}
__device__ inline float4 bf4tof(ushort4 h) {
    return make_float4(__uint_as_float((unsigned)h.x << 16),
                       __uint_as_float((unsigned)h.y << 16),
                       __uint_as_float((unsigned)h.z << 16),
                       __uint_as_float((unsigned)h.w << 16));
}

// ---------------- degree ----------------
__global__ void k_deg(const int* __restrict__ dst, unsigned* __restrict__ deg, int E) {
    int e = blockIdx.x * 256 + threadIdx.x;
    if (e < E) atomicAdd(&deg[dst[e]], 1u);
}

__global__ void k_dinv(const unsigned* __restrict__ deg, float* __restrict__ dinv, int n) {
    int i = blockIdx.x * 256 + threadIdx.x;
    if (i < n) dinv[i] = rsqrtf((float)deg[i] + 1.0f);  // +1 = self loop
}

// ---------------- hierarchical exclusive scan of deg -> rowptr ----------------
__global__ __launch_bounds__(1024) void k_scan1(const unsigned* __restrict__ deg,
                                                int* __restrict__ rowptr, int* __restrict__ bsum, int n) {
    __shared__ int wsum[16];
    int i = blockIdx.x * 1024 + threadIdx.x;
    int lane = threadIdx.x & 63, wid = threadIdx.x >> 6;
    int v = (i < n) ? (int)deg[i] : 0;
    int incl = v;
    #pragma unroll
    for (int off = 1; off < 64; off <<= 1) {
        int t = __shfl_up(incl, off, 64);
        if (lane >= off) incl += t;
    }
    if (lane == 63) wsum[wid] = incl;
    __syncthreads();
    int woff = 0;
    #pragma unroll
    for (int w = 0; w < 16; ++w) woff += (w < wid) ? wsum[w] : 0;
    if (i < n) rowptr[i] = woff + incl - v;          // block-local exclusive
    if (threadIdx.x == 1023) bsum[blockIdx.x] = woff + incl;  // block total
}

__global__ void k_scan2(int* __restrict__ bsum, int* __restrict__ rowptr_n, int nb) {
    int lane = threadIdx.x;   // 64 threads, nb <= 64
    int v = (lane < nb) ? bsum[lane] : 0;
    int incl = v;
    #pragma unroll
    for (int off = 1; off < 64; off <<= 1) {
        int t = __shfl_up(incl, off, 64);
        if (lane >= off) incl += t;
    }
    if (lane < nb) bsum[lane] = incl - v;            // exclusive block offsets
    if (lane == 63) *rowptr_n = incl;                // grand total
}

__global__ __launch_bounds__(1024) void k_scan3(int* __restrict__ rowptr, int* __restrict__ cursor,
                                                const int* __restrict__ bsum, int n) {
    int i = blockIdx.x * 1024 + threadIdx.x;
    if (i < n) {
        int r = rowptr[i] + bsum[blockIdx.x];
        rowptr[i] = r;
        cursor[i] = r;
    }
}

// ---------------- CSR fill: group edge sources by dst ----------------
__global__ void k_fill(const int* __restrict__ src, const int* __restrict__ dst,
                       int* __restrict__ cursor, int* __restrict__ csr_src, int E) {
    int e = blockIdx.x * 256 + threadIdx.x;
    if (e < E) {
        int p = atomicAdd(&cursor[dst[e]], 1);
        csr_src[p] = src[e];
    }
}

// ---------------- graph boundaries from sorted batch ----------------
__global__ void k_gptr(const int* __restrict__ batch, int* __restrict__ gptr, int n) {
    int g = blockIdx.x * 256 + threadIdx.x;
    if (g > GG) return;
    int lo = 0, hi = n;                       // first index with batch[i] >= g
    while (lo < hi) { int mid = (lo + hi) >> 1; if (batch[mid] < g) lo = mid + 1; else hi = mid; }
    gptr[g] = lo;
}

// ---------------- GEMM: H2 = bf16( (bn(X) @ W) * dinv[row] ) ----------------
// If sc!=null, staged X gets x*sc[f]+sh[f], relu (fused BN of previous layer).
#define TM 64
__global__ __launch_bounds__(256) void k_gemm(const float* __restrict__ X,
                                              const float* __restrict__ W,
                                              const float* __restrict__ dinv,
                                              const float* __restrict__ sc,
                                              const float* __restrict__ sh,
                                              unsigned short* __restrict__ H, int n) {
    __shared__ float xs[TM][128];          // 32 KB
    int row0 = blockIdx.x * TM;
    int tid = threadIdx.x;
    const float4* Xv = (const float4*)X;   // row stride = 32 float4
    float4* xsv = (float4*)xs;
    #pragma unroll
    for (int i = 0; i < TM * 32 / 256; ++i) {
        int idx = tid + i * 256;
        int r = idx >> 5, c = idx & 31;
        float4 v = make_float4(0.f, 0.f, 0.f, 0.f);
        if (row0 + r < n) v = Xv[(size_t)(row0 + r) * 32 + c];
        if (sc) {
            float4 s4 = ((const float4*)sc)[c];
            float4 h4 = ((const float4*)sh)[c];
            v.x = fmaxf(fmaf(v.x, s4.x, h4.x), 0.f);
            v.y = fmaxf(fmaf(v.y, s4.y, h4.y), 0.f);
            v.z = fmaxf(fmaf(v.z, s4.z, h4.z), 0.f);
            v.w = fmaxf(fmaf(v.w, s4.w, h4.w), 0.f);
        }
        xsv[idx] = v;
    }
    __syncthreads();
    int tn = tid & 15, tm = tid >> 4;
    int c0 = tn * 8, r0 = tm * 4;
    float acc[4][8];
    #pragma unroll
    for (int r = 0; r < 4; ++r)
        #pragma unroll
        for (int c = 0; c < 8; ++c) acc[r][c] = 0.f;
    const float4* Wv = (const float4*)W;   // W cached in L1/L2 (64 KB, reused by all blocks)
    #pragma unroll 4
    for (int kb = 0; kb < 32; ++kb) {
        int k4 = kb * 4;
        float4 xv[4];
        #pragma unroll
        for (int r = 0; r < 4; ++r) xv[r] = *(const float4*)&xs[r0 + r][k4];
        #pragma unroll
        for (int kk = 0; kk < 4; ++kk) {
            float4 w0 = Wv[(k4 + kk) * 32 + tn * 2];
            float4 w1 = Wv[(k4 + kk) * 32 + tn * 2 + 1];
            #pragma unroll
            for (int r = 0; r < 4; ++r) {
                float x = ((const float*)&xv[r])[kk];
                acc[r][0] = fmaf(x, w0.x, acc[r][0]);
                acc[r][1] = fmaf(x, w0.y, acc[r][1]);
                acc[r][2] = fmaf(x, w0.z, acc[r][2]);
                acc[r][3] = fmaf(x, w0.w, acc[r][3]);
                acc[r][4] = fmaf(x, w1.x, acc[r][4]);
                acc[r][5] = fmaf(x, w1.y, acc[r][5]);
                acc[r][6] = fmaf(x, w1.z, acc[r][6]);
                acc[r][7] = fmaf(x, w1.w, acc[r][7]);
            }
        }
    }
    #pragma unroll
    for (int r = 0; r < 4; ++r) {
        int row = row0 + r0 + r;
        if (row < n) {
            float dv = dinv[row];
            unsigned w[4];
            #pragma unroll
            for (int c = 0; c < 4; ++c) {
                unsigned lo = bf16_rn(acc[r][2 * c] * dv);
                unsigned hi = bf16_rn(acc[r][2 * c + 1] * dv);
                w[c] = lo | (hi << 16);
            }
            *(uint4*)&H[(size_t)row * 128 + c0] = make_uint4(w[0], w[1], w[2], w[3]);
        }
    }
}

// ---------------- pull aggregation: A[d] = dinv[d] * (H2[d] + sum H2[src]) ----------------
__global__ __launch_bounds__(256) void k_aggregate(const int* __restrict__ rowptr, const int* __restrict__ csr_src,
                                                   const float* __restrict__ dinv,
                                                   const unsigned short* __restrict__ H2,
                                                   float* __restrict__ A, int n) {
    int node = blockIdx.x * 8 + (threadIdx.x >> 5);
    if (node >= n) return;
    int lane = threadIdx.x & 31;
    int beg = rowptr[node], end = rowptr[node + 1];
    float dv = dinv[node];
    const ushort4* Hv = (const ushort4*)H2;              // row = 32 ushort4
    float4 self = bf4tof(Hv[(size_t)node * 32 + lane]);  // self loop
    float4 acc = self;
    float4 acc2 = make_float4(0.f, 0.f, 0.f, 0.f);
    int e = beg;
    for (; e + 1 < end; e += 2) {
        int s0 = csr_src[e], s1 = csr_src[e + 1];
        float4 h0 = bf4tof(Hv[(size_t)s0 * 32 + lane]);
        float4 h1 = bf4tof(Hv[(size_t)s1 * 32 + lane]);
        acc.x += h0.x;  acc.y += h0.y;  acc.z += h0.z;  acc.w += h0.w;
        acc2.x += h1.x; acc2.y += h1.y; acc2.z += h1.z; acc2.w += h1.w;
    }
    if (e < end) {
        int s0 = csr_src[e];
        float4 h0 = bf4tof(Hv[(size_t)s0 * 32 + lane]);
        acc.x += h0.x; acc.y += h0.y; acc.z += h0.z; acc.w += h0.w;
    }
    acc.x = (acc.x + acc2.x) * dv;
    acc.y = (acc.y + acc2.y) * dv;
    acc.z = (acc.z + acc2.z) * dv;
    acc.w = (acc.w + acc2.w) * dv;
    *(float4*)&A[(size_t)node * 128 + lane * 4] = acc;
}

// ---------------- BN stats: per-block partial sum & sumsq (no atomics) ----------------
__global__ __launch_bounds__(256) void k_stats(const float* __restrict__ X, float* __restrict__ partials, int n) {
    __shared__ float s0[256], s1[256];
    int tid = threadIdx.x;
    int f = tid & 127, sub = tid >> 7;
    float s = 0.f, ss = 0.f;
    for (int r = blockIdx.x * 2 + sub; r < n; r += NSB * 2) {
        float v = X[(size_t)r * 128 + f];
        s += v;
        ss = fmaf(v, v, ss);
    }
    s0[tid] = s; s1[tid] = ss;
    __syncthreads();
    if (tid < 128) {
        partials[(size_t)blockIdx.x * 256 + f]       = s0[tid] + s0[tid + 128];
        partials[(size_t)blockIdx.x * 256 + 128 + f] = s1[tid] + s1[tid + 128];
    }
}

// ---------------- finalize stats -> scale/shift ----------------
__global__ __launch_bounds__(128) void k_finstats(const float* __restrict__ partials,
                                                  const float* __restrict__ gamma, const float* __restrict__ beta,
                                                  float* __restrict__ sc, float* __restrict__ sh, int n) {
    int f = threadIdx.x;
    float s = 0.f, q = 0.f;
    for (int b = 0; b < NSB; ++b) {
        s += partials[(size_t)b * 256 + f];
        q += partials[(size_t)b * 256 + 128 + f];
    }
    float invN = 1.0f / (float)n;
    float mu = s * invN;
    float var = fmaf(-mu, mu, q * invN);
    float scale = gamma[f] * rsqrtf(var + EPSV);
    sc[f] = scale;
    sh[f] = fmaf(-mu, scale, beta[f]);
}

// ---------------- pooling over sorted batch: mean & max, fused final BN+ReLU ----------------
__global__ __launch_bounds__(256) void k_pool(const float* __restrict__ X, const int* __restrict__ gptr,
                                              const float* __restrict__ sc, const float* __restrict__ sh,
                                              float* __restrict__ pooled) {
    __shared__ float shm[256];
    int g = blockIdx.x;
    int t = threadIdx.x;
    int f = t & 127, sub = t >> 7;
    int beg = gptr[g], end = gptr[g + 1];
    float scf = sc[f], shf = sh[f];
    float s = 0.f, m = 0.f;
    for (int r = beg + sub; r < end; r += 2) {
        float v = fmaxf(fmaf(X[(size_t)r * 128 + f], scf, shf), 0.f);
        s += v; m = fmaxf(m, v);
    }
    shm[t] = s;
    __syncthreads();
    if (sub == 0) {
        int c = end - beg;
        float inv = (c > 0) ? 1.0f / (float)c : 0.f;
        pooled[(size_t)g * 256 + f] = (s + shm[t + 128]) * inv;
    }
    __syncthreads();
    shm[t] = m;
    __syncthreads();
    if (sub == 1) {
        pooled[(size_t)g * 256 + 128 + f] = fmaxf(m, shm[t - 128]);  // 0 for empty graph = reference
    }
}

// ---------------- MLP ----------------
__global__ __launch_bounds__(256) void k_mlp1(const float* __restrict__ pooled, const float* __restrict__ W1,
                                              const float* __restrict__ b1, float* __restrict__ H1) {
    __shared__ float grow[256];
    int gi = blockIdx.x, t = threadIdx.x;
    grow[t] = pooled[(size_t)gi * 256 + t];
    __syncthreads();
    float acc = b1[t];
    #pragma unroll 8
    for (int k = 0; k < 256; ++k) acc = fmaf(grow[k], W1[k * 256 + t], acc);
    H1[gi * 256 + t] = fmaxf(acc, 0.f);
}

__global__ __launch_bounds__(128) void k_mlp2(const float* __restrict__ H1, const float* __restrict__ W2,
                                              const float* __restrict__ b2, float* __restrict__ H2) {
    __shared__ float row[256];
    int gi = blockIdx.x, t = threadIdx.x;
    row[t] = H1[gi * 256 + t];
    row[t + 128] = H1[gi * 256 + t + 128];
    __syncthreads();
    float acc = b2[t];
    #pragma unroll 8
    for (int k = 0; k < 256; ++k) acc = fmaf(row[k], W2[k * 128 + t], acc);
    H2[gi * 128 + t] = fmaxf(acc, 0.f);
}

__global__ __launch_bounds__(256) void k_mlp3(const float* __restrict__ H2, const float* __restrict__ W3,
                                              const float* __restrict__ b3, float* __restrict__ out) {
    int gi = blockIdx.x * 4 + (threadIdx.x >> 6);
    int lane = threadIdx.x & 63;
    float v = H2[gi * 128 + lane] * W3[lane] + H2[gi * 128 + 64 + lane] * W3[64 + lane];
    #pragma unroll
    for (int off = 32; off; off >>= 1) v += __shfl_down(v, off);
    if (lane == 0) out[gi] = v + b3[0];
}

extern "C" void kernel_launch(void* const* d_in, const int* in_sizes, int n_in,
                              void* d_out, int out_size, void* d_ws, size_t ws_size,
                              hipStream_t stream) {
    const float* x      = (const float*)d_in[0];
    const int*   ei     = (const int*)d_in[1];
    const int*   batch  = (const int*)d_in[2];
    const float* convW0 = (const float*)d_in[3];
    const float* convW  = (const float*)d_in[4];
    // d_in[5] convb: cancels inside BatchNorm, unused
    const float* gamma  = (const float*)d_in[6];
    const float* beta   = (const float*)d_in[7];
    const float* mW1    = (const float*)d_in[8];
    const float* mb1    = (const float*)d_in[9];
    const float* mW2    = (const float*)d_in[10];
    const float* mb2    = (const float*)d_in[11];
    const float* mW3    = (const float*)d_in[12];
    const float* mb3    = (const float*)d_in[13];
    float* out = (float*)d_out;

    const int E = in_sizes[1] / 2;
    const int n = in_sizes[0] / FH;
    const int npad = (n + 4) & ~3;
    const int nb = (n + 1023) / 1024;

    // workspace layout (16B-aligned chunks)
    float*          A     = (float*)d_ws;                     // n*128 f32 slot; used as bf16 H2 (n*128 ushort)
    unsigned short* H2b   = (unsigned short*)A;
    float*    B       = A + (size_t)n * FH;                   // n*128 f32 (aggregate out)
    float*    dinv    = B + (size_t)n * FH;                   // n
    unsigned* deg     = (unsigned*)(dinv + n);                // n
    float*    parts   = (float*)(deg + n);                    // NSB*256
    float*    sc      = parts + (size_t)NSB * 256;            // 128
    float*    sh      = sc + 128;                             // 128
    float*    pooled  = sh + 128;                             // G*256
    float*    h1      = pooled + (size_t)GG * 256;            // G*256
    float*    h2      = h1 + (size_t)GG * 256;                // G*128
    int*      gptr    = (int*)(h2 + (size_t)GG * FH);         // G+1 (pad 4)
    int*      rowptr  = gptr + ((GG + 4) & ~3);               // n+1 (padded)
    int*      cursor  = rowptr + npad;                        // n
    int*      bsum    = cursor + npad;                        // 64
    int*      csrsrc  = bsum + 64;                            // E

    const int* srcI = ei;
    const int* dstI = ei + E;

    // ---- CSR build + graph boundaries ----
    hipMemsetAsync(deg, 0, (size_t)n * sizeof(unsigned), stream);
    k_deg<<<(E + 255) / 256, 256, 0, stream>>>(dstI, deg, E);
    k_dinv<<<(n + 255) / 256, 256, 0, stream>>>(deg, dinv, n);
    k_scan1<<<nb, 1024, 0, stream>>>(deg, rowptr, bsum, n);
    k_scan2<<<1, 64, 0, stream>>>(bsum, rowptr + n, nb);
    k_scan3<<<nb, 1024, 0, stream>>>(rowptr, cursor, bsum, n);
    k_fill<<<(E + 255) / 256, 256, 0, stream>>>(srcI, dstI, cursor, csrsrc, E);
    k_gptr<<<(GG + 1 + 255) / 256, 256, 0, stream>>>(batch, gptr, n);

    const float* Ws[3] = {convW0, convW, convW + FH * FH};
    const float* xin = x;

    for (int l = 0; l < 3; ++l) {
        const float* scl = (l == 0) ? nullptr : sc;
        const float* shl = (l == 0) ? nullptr : sh;
        k_gemm<<<(n + TM - 1) / TM, 256, 0, stream>>>(xin, Ws[l], dinv, scl, shl, H2b, n);
        k_aggregate<<<(n + 7) / 8, 256, 0, stream>>>(rowptr, csrsrc, dinv, H2b, B, n);
        k_stats<<<NSB, 256, 0, stream>>>(B, parts, n);
        k_finstats<<<1, 128, 0, stream>>>(parts, gamma + l * FH, beta + l * FH, sc, sh, n);
        xin = B;   // next GEMM applies sc/sh on the fly
    }

    // pooling (applies layer-3 BN+ReLU on the fly), then MLP
    k_pool<<<GG, 256, 0, stream>>>(B, gptr, sc, sh, pooled);
    k_mlp1<<<GG, 256, 0, stream>>>(pooled, mW1, mb1, h1);
    k_mlp2<<<GG, 128, 0, stream>>>(h1, mW2, mb2, h2);
    k_mlp3<<<GG / 4, 256, 0, stream>>>(h2, mW3, mb3, out);
}

// Round 5
// 478.872 us; speedup vs baseline: 9.6516x; 1.1680x over previous
//
#include <hip/hip_runtime.h>

// GNN: 3x (GCNConv -> BN -> ReLU) -> mean/max pool per graph -> 3-layer MLP.
// N=50000 nodes, E=800000 edges, F=H=128, G=1024 graphs.
// conv bias cancels inside BatchNorm (mean-subtraction) -> skipped entirely.
// Aggregation: pull-style over CSR (no f32 atomics); H2 stored bf16.
// GEMM: MFMA 16x16x32 bf16, no LDS; W pre-packed into fragment order (k_wprep),
// A fragments loaded per-lane from global f32 with fused BN+ReLU -> bf16.
// BN-apply+ReLU folded into the NEXT consumer (GEMM staging / pooling).
// Pooling uses sorted `batch` (binary-searched boundaries) -> no atomics.

constexpr int FH = 128;     // feature dim
constexpr int GG = 1024;    // graphs
constexpr int NSB = 256;    // stats partial blocks
constexpr float EPSV = 1e-5f;

typedef __attribute__((ext_vector_type(8))) short short8v;   // 8 bf16 (4 VGPRs)
typedef __attribute__((ext_vector_type(4))) float f32x4;     // MFMA acc

__device__ inline unsigned short bf16_rn(float x) {
    unsigned u = __float_as_uint(x);
    unsigned r = (u + 0x7FFFu + ((u >> 16) & 1u)) >> 16;
    return (unsigned short)r;
}
__device__ inline float4 bf4tof(ushort4 h) {
    return make_float4(__uint_as_float((unsigned)h.x << 16),
                       __uint_as_float((unsigned)h.y << 16),
                       __uint_as_float((unsigned)h.z << 16),
                       __uint_as_float((unsigned)h.w << 16));
}

// ---------------- degree ----------------
__global__ void k_deg(const int* __restrict__ dst, unsigned* __restrict__ deg, int E) {
    int e = blockIdx.x * 256 + threadIdx.x;
    if (e < E) atomicAdd(&deg[dst[e]], 1u);
}

__global__ void k_dinv(const unsigned* __restrict__ deg, float* __restrict__ dinv, int n) {
    int i = blockIdx.x * 256 + threadIdx.x;
    if (i < n) dinv[i] = rsqrtf((float)deg[i] + 1.0f);  // +1 = self loop
}

// ---------------- hierarchical exclusive scan of deg -> rowptr ----------------
__global__ __launch_bounds__(1024) void k_scan1(const unsigned* __restrict__ deg,
                                                int* __restrict__ rowptr, int* __restrict__ bsum, int n) {
    __shared__ int wsum[16];
    int i = blockIdx.x * 1024 + threadIdx.x;
    int lane = threadIdx.x & 63, wid = threadIdx.x >> 6;
    int v = (i < n) ? (int)deg[i] : 0;
    int incl = v;
    #pragma unroll
    for (int off = 1; off < 64; off <<= 1) {
        int t = __shfl_up(incl, off, 64);
        if (lane >= off) incl += t;
    }
    if (lane == 63) wsum[wid] = incl;
    __syncthreads();
    int woff = 0;
    #pragma unroll
    for (int w = 0; w < 16; ++w) woff += (w < wid) ? wsum[w] : 0;
    if (i < n) rowptr[i] = woff + incl - v;          // block-local exclusive
    if (threadIdx.x == 1023) bsum[blockIdx.x] = woff + incl;  // block total
}

__global__ void k_scan2(int* __restrict__ bsum, int* __restrict__ rowptr_n, int nb) {
    int lane = threadIdx.x;   // 64 threads, nb <= 64
    int v = (lane < nb) ? bsum[lane] : 0;
    int incl = v;
    #pragma unroll
    for (int off = 1; off < 64; off <<= 1) {
        int t = __shfl_up(incl, off, 64);
        if (lane >= off) incl += t;
    }
    if (lane < nb) bsum[lane] = incl - v;            // exclusive block offsets
    if (lane == 63) *rowptr_n = incl;                // grand total
}

__global__ __launch_bounds__(1024) void k_scan3(int* __restrict__ rowptr, int* __restrict__ cursor,
                                                const int* __restrict__ bsum, int n) {
    int i = blockIdx.x * 1024 + threadIdx.x;
    if (i < n) {
        int r = rowptr[i] + bsum[blockIdx.x];
        rowptr[i] = r;
        cursor[i] = r;
    }
}

// ---------------- CSR fill: group edge sources by dst ----------------
__global__ void k_fill(const int* __restrict__ src, const int* __restrict__ dst,
                       int* __restrict__ cursor, int* __restrict__ csr_src, int E) {
    int e = blockIdx.x * 256 + threadIdx.x;
    if (e < E) {
        int p = atomicAdd(&cursor[dst[e]], 1);
        csr_src[p] = src[e];
    }
}

// ---------------- graph boundaries from sorted batch ----------------
__global__ void k_gptr(const int* __restrict__ batch, int* __restrict__ gptr, int n) {
    int g = blockIdx.x * 256 + threadIdx.x;
    if (g > GG) return;
    int lo = 0, hi = n;                       // first index with batch[i] >= g
    while (lo < hi) { int mid = (lo + hi) >> 1; if (batch[mid] < g) lo = mid + 1; else hi = mid; }
    gptr[g] = lo;
}

// ---------------- W prep: pack 3 layers of W into MFMA B-fragment order ----------------
// Wt[l] flat ushort idx o = (((nt*4+kb)*4 + hi)*16 + c)*8 + j
//   <- bf16(W_l[(kb*32 + hi*8 + j)*128 + nt*16 + c])
// so lane L's B-frag (nt,kb) = short8 at Wt_l + (nt*4+kb)*512 + L*8  (coalesced).
__global__ void k_wprep(const float* __restrict__ W0, const float* __restrict__ W12,
                        unsigned short* __restrict__ Wt) {
    int t = blockIdx.x * 256 + threadIdx.x;          // 0 .. 3*16384-1
    int l = t >> 14, o = t & 16383;
    const float* W = (l == 0) ? W0 : W12 + (size_t)(l - 1) * 16384;
    int j = o & 7, c = (o >> 3) & 15, hi = (o >> 7) & 3, kb = (o >> 9) & 3, nt = o >> 11;
    int k = kb * 32 + hi * 8 + j;
    int col = nt * 16 + c;
    Wt[t] = bf16_rn(W[k * 128 + col]);
}

// ---------------- GEMM: H2 = bf16( (bn_relu(X) @ W) * dinv[row] ), MFMA ----------------
// block = 256 threads = 4 waves; wave w owns rows [blk*64 + w*16, +16), all 128 cols.
__global__ __launch_bounds__(256) void k_gemm(const float* __restrict__ X,
                                              const unsigned short* __restrict__ Wt,
                                              const float* __restrict__ dinv,
                                              const float* __restrict__ sc,
                                              const float* __restrict__ sh,
                                              unsigned short* __restrict__ H, int n) {
    int wave = threadIdx.x >> 6, L = threadIdx.x & 63;
    int hi = L >> 4, c16 = L & 15;
    int m0 = blockIdx.x * 64 + wave * 16;
    int arow = m0 + c16;                   // A-frag row this lane loads
    bool okA = arow < n;

    short8v aF[4];
    #pragma unroll
    for (int kb = 0; kb < 4; ++kb) {
        int kc = kb * 32 + hi * 8;
        float4 v0 = make_float4(0.f, 0.f, 0.f, 0.f);
        float4 v1 = v0;
        if (okA) {
            v0 = *(const float4*)&X[(size_t)arow * 128 + kc];
            v1 = *(const float4*)&X[(size_t)arow * 128 + kc + 4];
        }
        if (sc) {
            float4 s0 = *(const float4*)&sc[kc], s1 = *(const float4*)&sc[kc + 4];
            float4 h0 = *(const float4*)&sh[kc], h1 = *(const float4*)&sh[kc + 4];
            v0.x = fmaxf(fmaf(v0.x, s0.x, h0.x), 0.f);
            v0.y = fmaxf(fmaf(v0.y, s0.y, h0.y), 0.f);
            v0.z = fmaxf(fmaf(v0.z, s0.z, h0.z), 0.f);
            v0.w = fmaxf(fmaf(v0.w, s0.w, h0.w), 0.f);
            v1.x = fmaxf(fmaf(v1.x, s1.x, h1.x), 0.f);
            v1.y = fmaxf(fmaf(v1.y, s1.y, h1.y), 0.f);
            v1.z = fmaxf(fmaf(v1.z, s1.z, h1.z), 0.f);
            v1.w = fmaxf(fmaf(v1.w, s1.w, h1.w), 0.f);
        }
        short8v a;
        a[0] = (short)bf16_rn(v0.x); a[1] = (short)bf16_rn(v0.y);
        a[2] = (short)bf16_rn(v0.z); a[3] = (short)bf16_rn(v0.w);
        a[4] = (short)bf16_rn(v1.x); a[5] = (short)bf16_rn(v1.y);
        a[6] = (short)bf16_rn(v1.z); a[7] = (short)bf16_rn(v1.w);
        aF[kb] = a;
    }

    f32x4 acc[8];
    #pragma unroll
    for (int nt = 0; nt < 8; ++nt) {
        acc[nt][0] = 0.f; acc[nt][1] = 0.f; acc[nt][2] = 0.f; acc[nt][3] = 0.f;
    }
    #pragma unroll
    for (int nt = 0; nt < 8; ++nt) {
        #pragma unroll
        for (int kb = 0; kb < 4; ++kb) {
            short8v bF = *(const short8v*)&Wt[(size_t)(nt * 4 + kb) * 512 + L * 8];
            acc[nt] = __builtin_amdgcn_mfma_f32_16x16x32_bf16(aF[kb], bF, acc[nt], 0, 0, 0);
        }
    }

    // epilogue: C row = m0 + hi*4 + reg, col = nt*16 + c16
    #pragma unroll
    for (int reg = 0; reg < 4; ++reg) {
        int row = m0 + hi * 4 + reg;
        if (row < n) {
            float dv = dinv[row];
            #pragma unroll
            for (int nt = 0; nt < 8; ++nt)
                H[(size_t)row * 128 + nt * 16 + c16] = bf16_rn(acc[nt][reg] * dv);
        }
    }
}

// ---------------- pull aggregation: A[d] = dinv[d] * (H2[d] + sum H2[src]) ----------------
__global__ __launch_bounds__(256) void k_aggregate(const int* __restrict__ rowptr, const int* __restrict__ csr_src,
                                                   const float* __restrict__ dinv,
                                                   const unsigned short* __restrict__ H2,
                                                   float* __restrict__ A, int n) {
    int node = blockIdx.x * 8 + (threadIdx.x >> 5);
    if (node >= n) return;
    int lane = threadIdx.x & 31;
    int beg = rowptr[node], end = rowptr[node + 1];
    float dv = dinv[node];
    const ushort4* Hv = (const ushort4*)H2;              // row = 32 ushort4
    float4 self = bf4tof(Hv[(size_t)node * 32 + lane]);  // self loop
    float4 acc = self;
    float4 acc2 = make_float4(0.f, 0.f, 0.f, 0.f);
    int e = beg;
    for (; e + 1 < end; e += 2) {
        int s0 = csr_src[e], s1 = csr_src[e + 1];
        float4 h0 = bf4tof(Hv[(size_t)s0 * 32 + lane]);
        float4 h1 = bf4tof(Hv[(size_t)s1 * 32 + lane]);
        acc.x += h0.x;  acc.y += h0.y;  acc.z += h0.z;  acc.w += h0.w;
        acc2.x += h1.x; acc2.y += h1.y; acc2.z += h1.z; acc2.w += h1.w;
    }
    if (e < end) {
        int s0 = csr_src[e];
        float4 h0 = bf4tof(Hv[(size_t)s0 * 32 + lane]);
        acc.x += h0.x; acc.y += h0.y; acc.z += h0.z; acc.w += h0.w;
    }
    acc.x = (acc.x + acc2.x) * dv;
    acc.y = (acc.y + acc2.y) * dv;
    acc.z = (acc.z + acc2.z) * dv;
    acc.w = (acc.w + acc2.w) * dv;
    *(float4*)&A[(size_t)node * 128 + lane * 4] = acc;
}

// ---------------- BN stats: per-block partial sum & sumsq (no atomics) ----------------
__global__ __launch_bounds__(256) void k_stats(const float* __restrict__ X, float* __restrict__ partials, int n) {
    __shared__ float s0[256], s1[256];
    int tid = threadIdx.x;
    int f = tid & 127, sub = tid >> 7;
    float s = 0.f, ss = 0.f;
    for (int r = blockIdx.x * 2 + sub; r < n; r += NSB * 2) {
        float v = X[(size_t)r * 128 + f];
        s += v;
        ss = fmaf(v, v, ss);
    }
    s0[tid] = s; s1[tid] = ss;
    __syncthreads();
    if (tid < 128) {
        partials[(size_t)blockIdx.x * 256 + f]       = s0[tid] + s0[tid + 128];
        partials[(size_t)blockIdx.x * 256 + 128 + f] = s1[tid] + s1[tid + 128];
    }
}

// ---------------- finalize stats -> scale/shift ----------------
__global__ __launch_bounds__(128) void k_finstats(const float* __restrict__ partials,
                                                  const float* __restrict__ gamma, const float* __restrict__ beta,
                                                  float* __restrict__ sc, float* __restrict__ sh, int n) {
    int f = threadIdx.x;
    float s = 0.f, q = 0.f;
    for (int b = 0; b < NSB; ++b) {
        s += partials[(size_t)b * 256 + f];
        q += partials[(size_t)b * 256 + 128 + f];
    }
    float invN = 1.0f / (float)n;
    float mu = s * invN;
    float var = fmaf(-mu, mu, q * invN);
    float scale = gamma[f] * rsqrtf(var + EPSV);
    sc[f] = scale;
    sh[f] = fmaf(-mu, scale, beta[f]);
}

// ---------------- pooling over sorted batch: mean & max, fused final BN+ReLU ----------------
__global__ __launch_bounds__(256) void k_pool(const float* __restrict__ X, const int* __restrict__ gptr,
                                              const float* __restrict__ sc, const float* __restrict__ sh,
                                              float* __restrict__ pooled) {
    __shared__ float shm[256];
    int g = blockIdx.x;
    int t = threadIdx.x;
    int f = t & 127, sub = t >> 7;
    int beg = gptr[g], end = gptr[g + 1];
    float scf = sc[f], shf = sh[f];
    float s = 0.f, m = 0.f;
    for (int r = beg + sub; r < end; r += 2) {
        float v = fmaxf(fmaf(X[(size_t)r * 128 + f], scf, shf), 0.f);
        s += v; m = fmaxf(m, v);
    }
    shm[t] = s;
    __syncthreads();
    if (sub == 0) {
        int c = end - beg;
        float inv = (c > 0) ? 1.0f / (float)c : 0.f;
        pooled[(size_t)g * 256 + f] = (s + shm[t + 128]) * inv;
    }
    __syncthreads();
    shm[t] = m;
    __syncthreads();
    if (sub == 1) {
        pooled[(size_t)g * 256 + 128 + f] = fmaxf(m, shm[t - 128]);  // 0 for empty graph = reference
    }
}

// ---------------- MLP ----------------
__global__ __launch_bounds__(256) void k_mlp1(const float* __restrict__ pooled, const float* __restrict__ W1,
                                              const float* __restrict__ b1, float* __restrict__ H1) {
    __shared__ float grow[256];
    int gi = blockIdx.x, t = threadIdx.x;
    grow[t] = pooled[(size_t)gi * 256 + t];
    __syncthreads();
    float acc = b1[t];
    #pragma unroll 8
    for (int k = 0; k < 256; ++k) acc = fmaf(grow[k], W1[k * 256 + t], acc);
    H1[gi * 256 + t] = fmaxf(acc, 0.f);
}

__global__ __launch_bounds__(128) void k_mlp2(const float* __restrict__ H1, const float* __restrict__ W2,
                                              const float* __restrict__ b2, float* __restrict__ H2) {
    __shared__ float row[256];
    int gi = blockIdx.x, t = threadIdx.x;
    row[t] = H1[gi * 256 + t];
    row[t + 128] = H1[gi * 256 + t + 128];
    __syncthreads();
    float acc = b2[t];
    #pragma unroll 8
    for (int k = 0; k < 256; ++k) acc = fmaf(row[k], W2[k * 128 + t], acc);
    H2[gi * 128 + t] = fmaxf(acc, 0.f);
}

__global__ __launch_bounds__(256) void k_mlp3(const float* __restrict__ H2, const float* __restrict__ W3,
                                              const float* __restrict__ b3, float* __restrict__ out) {
    int gi = blockIdx.x * 4 + (threadIdx.x >> 6);
    int lane = threadIdx.x & 63;
    float v = H2[gi * 128 + lane] * W3[lane] + H2[gi * 128 + 64 + lane] * W3[64 + lane];
    #pragma unroll
    for (int off = 32; off; off >>= 1) v += __shfl_down(v, off);
    if (lane == 0) out[gi] = v + b3[0];
}

extern "C" void kernel_launch(void* const* d_in, const int* in_sizes, int n_in,
                              void* d_out, int out_size, void* d_ws, size_t ws_size,
                              hipStream_t stream) {
    const float* x      = (const float*)d_in[0];
    const int*   ei     = (const int*)d_in[1];
    const int*   batch  = (const int*)d_in[2];
    const float* convW0 = (const float*)d_in[3];
    const float* convW  = (const float*)d_in[4];
    // d_in[5] convb: cancels inside BatchNorm, unused
    const float* gamma  = (const float*)d_in[6];
    const float* beta   = (const float*)d_in[7];
    const float* mW1    = (const float*)d_in[8];
    const float* mb1    = (const float*)d_in[9];
    const float* mW2    = (const float*)d_in[10];
    const float* mb2    = (const float*)d_in[11];
    const float* mW3    = (const float*)d_in[12];
    const float* mb3    = (const float*)d_in[13];
    float* out = (float*)d_out;

    const int E = in_sizes[1] / 2;
    const int n = in_sizes[0] / FH;
    const int npad = (n + 4) & ~3;
    const int nb = (n + 1023) / 1024;

    // workspace layout (16B-aligned chunks)
    float*          A     = (float*)d_ws;                     // n*128 f32 slot; used as bf16 H2 (n*128 ushort)
    unsigned short* H2b   = (unsigned short*)A;
    float*    B       = A + (size_t)n * FH;                   // n*128 f32 (aggregate out)
    float*    dinv    = B + (size_t)n * FH;                   // n
    unsigned* deg     = (unsigned*)(dinv + n);                // n
    float*    parts   = (float*)(deg + n);                    // NSB*256
    float*    sc      = parts + (size_t)NSB * 256;            // 128
    float*    sh      = sc + 128;                             // 128
    float*    pooled  = sh + 128;                             // G*256
    float*    h1      = pooled + (size_t)GG * 256;            // G*256
    float*    h2      = h1 + (size_t)GG * 256;                // G*128
    int*      gptr    = (int*)(h2 + (size_t)GG * FH);         // G+1 (pad 4)
    int*      rowptr  = gptr + ((GG + 4) & ~3);               // n+1 (padded)
    int*      cursor  = rowptr + npad;                        // n
    int*      bsum    = cursor + npad;                        // 64
    int*      csrsrc  = bsum + 64;                            // E
    unsigned short* Wt = (unsigned short*)(csrsrc + ((E + 3) & ~3));  // 3*16384 ushorts

    const int* srcI = ei;
    const int* dstI = ei + E;

    // ---- CSR build + graph boundaries + W prep ----
    hipMemsetAsync(deg, 0, (size_t)n * sizeof(unsigned), stream);
    k_deg<<<(E + 255) / 256, 256, 0, stream>>>(dstI, deg, E);
    k_dinv<<<(n + 255) / 256, 256, 0, stream>>>(deg, dinv, n);
    k_scan1<<<nb, 1024, 0, stream>>>(deg, rowptr, bsum, n);
    k_scan2<<<1, 64, 0, stream>>>(bsum, rowptr + n, nb);
    k_scan3<<<nb, 1024, 0, stream>>>(rowptr, cursor, bsum, n);
    k_fill<<<(E + 255) / 256, 256, 0, stream>>>(srcI, dstI, cursor, csrsrc, E);
    k_gptr<<<(GG + 1 + 255) / 256, 256, 0, stream>>>(batch, gptr, n);
    k_wprep<<<3 * 16384 / 256, 256, 0, stream>>>(convW0, convW, Wt);

    const float* xin = x;

    for (int l = 0; l < 3; ++l) {
        const float* scl = (l == 0) ? nullptr : sc;
        const float* shl = (l == 0) ? nullptr : sh;
        k_gemm<<<(n + 63) / 64, 256, 0, stream>>>(xin, Wt + (size_t)l * 16384, dinv, scl, shl, H2b, n);
        k_aggregate<<<(n + 7) / 8, 256, 0, stream>>>(rowptr, csrsrc, dinv, H2b, B, n);
        k_stats<<<NSB, 256, 0, stream>>>(B, parts, n);
        k_finstats<<<1, 128, 0, stream>>>(parts, gamma + l * FH, beta + l * FH, sc, sh, n);
        xin = B;   // next GEMM applies sc/sh on the fly
    }

    // pooling (applies layer-3 BN+ReLU on the fly), then MLP
    k_pool<<<GG, 256, 0, stream>>>(B, gptr, sc, sh, pooled);
    k_mlp1<<<GG, 256, 0, stream>>>(pooled, mW1, mb1, h1);
    k_mlp2<<<GG, 128, 0, stream>>>(h1, mW2, mb2, h2);
    k_mlp3<<<GG / 4, 256, 0, stream>>>(h2, mW3, mb3, out);
}